// Round 18
// baseline (182.188 us; speedup 1.0000x reference)
//
#include <hip/hip_runtime.h>
#include <hip/hip_bf16.h>
#include <hip/hip_fp16.h>

// GraphSAGE edge classifier.
// v17 — prep LDS high-water cut 49.6->32.9 KB for 4 blocks/CU (was 3):
//       lin1 32 nodes/block (2 cols/thread), binning NBLK=512 chunk=6250
//       (stage 25.6KB). Rest = v16.
//  K0 memset   : gcur[NB] = 0
//  K1 prep     : blocks [0,512): hist->exscan->reserve->LDS sort->segment write
//                blocks [512,..): lin1 (yh=half(x@W1l), zh=half(x@W1r))
//  K2 sortagg  : per-bucket LDS counting sort -> row_csr/row_end + coalesced
//                elist writeback + fused agg1 -> ph, qh
//  K3 agg2     : CSR gather mean(ph) -> h2=relu(+b2+qh) -> Uh, Vh
//  K4 edge_out : out = log_softmax(Uh[src] + Vh[dst] + bc), 4 edges/thread

#define NBLK 512          // binning chunks (chunk = 6250)
#define BUCKET_BITS 8
#define BUCKET_SZ 256     // nodes per bucket
#define CAP 9216          // entries per bucket region (mean 8192, +11 sigma)
#define MAXNB 512
#define CHUNK_MAX 6400
#define LIN_NODES 32

struct __align__(16) H8 { __half2 a, b, c, d; };

// ---- K1: heterogeneous {local-sort binning} + lin1 -------------------------
// smem floats: max(lin1 = 32*129+128*32 = 8224, bin = (3*512+8+6400)=7944 ints)
__global__ __launch_bounds__(512) void prep_kernel(const int* __restrict__ ei,
                                                   int* __restrict__ gcur,
                                                   int* __restrict__ elist,
                                                   const float* __restrict__ x,
                                                   const float* __restrict__ W1l,
                                                   const float* __restrict__ W1r,
                                                   __half* __restrict__ yh,
                                                   __half* __restrict__ zh,
                                                   int E, int N, int NB, int chunk,
                                                   int nbin) {
  __shared__ float smem[LIN_NODES * 129 + 128 * 32];   // 32.9 KB, aliased
  int t = threadIdx.x;
  if ((int)blockIdx.x < nbin) {
    // ---- binning: hist -> exscan+reserve -> LDS sort -> segment write ----
    int* hist  = (int*)smem;            // MAXNB   (becomes local cursor)
    int* loc   = hist + MAXNB;          // MAXNB   (immutable local exscan)
    int* gbase = loc + MAXNB;           // MAXNB   (global dest base)
    int* wtmp  = gbase + MAXNB;         // 8
    int* stage = wtmp + 8;              // CHUNK_MAX
    int lane = t & 63, wid = t >> 6;
    for (int i = t; i < NB; i += 512) hist[i] = 0;
    __syncthreads();
    int s = blockIdx.x * chunk;
    int eend = s + chunk; if (eend > E) eend = E;
    int cnt = eend - s;
    for (int e = s + t; e < eend; e += 512)
      atomicAdd(&hist[ei[E + e] >> BUCKET_BITS], 1);
    __syncthreads();
    // exscan over NB bins (one element per thread, NB <= 512)
    {
      int v = (t < NB) ? hist[t] : 0;
      int incl = v;
#pragma unroll
      for (int d = 1; d < 64; d <<= 1) {
        int u = __shfl_up(incl, d);
        if (lane >= d) incl += u;
      }
      if (lane == 63) wtmp[wid] = incl;
      __syncthreads();
      if (t < 64) {
        int w = (t < 8) ? wtmp[t] : 0;
#pragma unroll
        for (int d = 1; d < 8; d <<= 1) {
          int u = __shfl_up(w, d);
          if (lane >= d) w += u;
        }
        if (t < 8) wtmp[t] = w;
      }
      __syncthreads();
      if (t < NB) {
        int excl = ((wid > 0) ? wtmp[wid - 1] : 0) + (incl - v);
        loc[t] = excl;
        gbase[t] = t * CAP + (v ? atomicAdd(&gcur[t], v) : 0);
        hist[t] = excl;                 // local scatter cursor
      }
    }
    __syncthreads();
    // local scatter into LDS stage (sorted by bucket)
    for (int e = s + t; e < eend; e += 512) {
      int src = ei[e];
      int dst = ei[E + e];
      int b = dst >> BUCKET_BITS;
      int pos = atomicAdd(&hist[b], 1);
      stage[pos] = ((dst & (BUCKET_SZ - 1)) << 17) | src;
    }
    __syncthreads();
    // segment-coalesced global write: position i belongs to bucket
    // lo = max{b : loc[b] <= i}; dest = gbase[lo] + (i - loc[lo]).
    for (int i = t; i < cnt; i += 512) {
      int lo = 0, hi = NB;
#pragma unroll 9
      while (hi - lo > 1) {
        int mid = (lo + hi) >> 1;
        if (loc[mid] <= i) lo = mid; else hi = mid;
      }
      elist[gbase[lo] + (i - loc[lo])] = stage[i];
    }
  } else {
    // ---- lin1: 32 nodes per block, 2 output cols per thread ----
    float* Xs = smem;                      // 32*129
    float* Ws = smem + LIN_NODES * 129;    // 128*32
    int nb = ((int)blockIdx.x - nbin) * LIN_NODES;
    for (int i = t; i < 128 * 16; i += 512) {
      int kk = i >> 4, c = i & 15;
      Ws[kk * 32 + c] = W1l[i];
      Ws[kk * 32 + 16 + c] = W1r[i];
    }
    const float4* xg = (const float4*)(x + (size_t)nb * 128);
    for (int i4 = t; i4 < LIN_NODES * 32; i4 += 512) {
      int r = i4 >> 5, c4 = (i4 & 31) * 4;
      float4 val = make_float4(0.f, 0.f, 0.f, 0.f);
      if (nb + r < N) val = xg[i4];
      float* dp = &Xs[r * 129 + c4];
      dp[0] = val.x; dp[1] = val.y; dp[2] = val.z; dp[3] = val.w;
    }
    __syncthreads();
    int n = t & 31, cg = t >> 5;        // node, col-group (2 cols each)
    int c = cg * 2;
    float a0 = 0.f, a1 = 0.f;
    for (int kk = 0; kk < 128; ++kk) {
      float xv = Xs[n * 129 + kk];
      const float* wr = &Ws[kk * 32 + c];
      a0 += xv * wr[0]; a1 += xv * wr[1];
    }
    int node = nb + n;
    if (node < N) {
      __half2 h01 = __floats2half2_rn(a0, a1);
      if (c < 16) ((__half2*)(yh + (size_t)node * 16 + c))[0] = h01;
      else        ((__half2*)(zh + (size_t)node * 16 + (c - 16)))[0] = h01;
    }
  }
}

// ---- K2: fused per-bucket counting sort + agg1 ------------------------------
__global__ __launch_bounds__(512) void sortagg_kernel(int* __restrict__ elist,
                                                      const int* __restrict__ gcur,
                                                      int* __restrict__ row_csr,
                                                      int* __restrict__ row_end,
                                                      const __half* __restrict__ yh,
                                                      const __half* __restrict__ zh,
                                                      const float* __restrict__ b1,
                                                      const float* __restrict__ W2l,
                                                      const float* __restrict__ W2r,
                                                      __half* __restrict__ ph,
                                                      __half* __restrict__ qh, int N) {
  extern __shared__ int sm[];
  int* sorted = sm;                    // CAP
  int* hist   = sm + CAP;              // 256
  int* wtmp   = hist + 256;            // 4
  float* Wl_s = (float*)(wtmp + 4);    // 256
  float* Wr_s = Wl_s + 256;            // 256
  float* b_s  = Wr_s + 256;            // 16
  int t = threadIdx.x;
  int b = blockIdx.x;
  int lane = t & 63, wid = t >> 6;
  if (t < 256) { Wl_s[t] = W2l[t]; Wr_s[t] = W2r[t]; hist[t] = 0; }
  else if (t < 272) b_s[t - 256] = b1[t - 256];
  int beg = b * CAP;
  int cnt = gcur[b];
  if (cnt > CAP) cnt = CAP;   // statistically unreachable
  __syncthreads();
  // pass 1: histogram from global
  for (int i = t; i < cnt; i += 512)
    atomicAdd(&hist[((unsigned)elist[beg + i]) >> 17], 1);
  __syncthreads();
  // exscan hist[0..255]
  {
    int v = (t < 256) ? hist[t] : 0;
    int incl = v;
#pragma unroll
    for (int d = 1; d < 64; d <<= 1) {
      int u = __shfl_up(incl, d);
      if (lane >= d) incl += u;
    }
    if (t < 256 && lane == 63) wtmp[wid] = incl;
    __syncthreads();
    if (t < 64) {
      int w = (t < 4) ? wtmp[t] : 0;
#pragma unroll
      for (int d = 1; d < 4; d <<= 1) {
        int u = __shfl_up(w, d);
        if (lane >= d) w += u;
      }
      if (t < 4) wtmp[t] = w;
    }
    __syncthreads();
    if (t < 256) {
      int excl = ((wid > 0) ? wtmp[wid - 1] : 0) + (incl - v);
      hist[t] = excl;                       // scatter cursor
      int node = (b << BUCKET_BITS) + t;
      if (node < N) row_csr[node] = beg + excl;
    }
  }
  __syncthreads();
  // pass 2: scatter from global (L2-hot) into LDS
  for (int i = t; i < cnt; i += 512) {
    unsigned ent = (unsigned)elist[beg + i];
    int pos = atomicAdd(&hist[ent >> 17], 1);
    sorted[pos] = ent & 0x1FFFF;
  }
  __syncthreads();
  if (t < 256) {
    int node = (b << BUCKET_BITS) + t;
    if (node < N) row_end[node] = beg + hist[t];
  }
  // coalesced writeback for agg2
  for (int i = t; i < cnt; i += 512) elist[beg + i] = sorted[i];
  // ---- fused agg1: 256 nodes, 8 lanes/node, 4 passes of 64 nodes ----
  const __half2* yh2 = (const __half2*)yh;
  int base = b << BUCKET_BITS;
  int k = t & 7;
#pragma unroll
  for (int pass = 0; pass < 4; ++pass) {
    int dl = pass * 64 + (t >> 3);
    int node = base + dl;
    if (node < N) {
      int rbeg = dl ? hist[dl - 1] : 0;   // hist = end offsets after scatter
      int rend = hist[dl];
      float a0 = 0.f, a1 = 0.f;
      int j = rbeg;
      for (; j + 4 <= rend; j += 4) {
        int s0 = sorted[j], s1 = sorted[j + 1];
        int s2 = sorted[j + 2], s3 = sorted[j + 3];
        float2 v0 = __half22float2(yh2[(size_t)s0 * 8 + k]);
        float2 v1 = __half22float2(yh2[(size_t)s1 * 8 + k]);
        float2 v2 = __half22float2(yh2[(size_t)s2 * 8 + k]);
        float2 v3 = __half22float2(yh2[(size_t)s3 * 8 + k]);
        a0 += v0.x + v1.x + v2.x + v3.x;
        a1 += v0.y + v1.y + v2.y + v3.y;
      }
      for (; j < rend; ++j) {
        float2 v = __half22float2(yh2[(size_t)sorted[j] * 8 + k]);
        a0 += v.x; a1 += v.y;
      }
      int deg = rend - rbeg;
      float inv = 1.f / (float)(deg > 0 ? deg : 1);
      float2 zv = __half22float2(((const __half2*)zh)[(size_t)node * 8 + k]);
      float h0 = fmaxf(a0 * inv + b_s[2 * k]     + zv.x, 0.f);
      float h1 = fmaxf(a1 * inv + b_s[2 * k + 1] + zv.y, 0.f);
      float pa0 = 0.f, pa1 = 0.f, qa0 = 0.f, qa1 = 0.f;
      int c0 = 2 * k;
#pragma unroll
      for (int kk2 = 0; kk2 < 8; ++kk2) {
        float ha = __shfl(h0, kk2, 8);
        float hb = __shfl(h1, kk2, 8);
        int r0 = 2 * kk2 * 16, r1 = r0 + 16;
        pa0 += ha * Wl_s[r0 + c0]     + hb * Wl_s[r1 + c0];
        pa1 += ha * Wl_s[r0 + c0 + 1] + hb * Wl_s[r1 + c0 + 1];
        qa0 += ha * Wr_s[r0 + c0]     + hb * Wr_s[r1 + c0];
        qa1 += ha * Wr_s[r0 + c0 + 1] + hb * Wr_s[r1 + c0 + 1];
      }
      ((__half2*)ph)[(size_t)node * 8 + k] = __floats2half2_rn(pa0, pa1);
      ((__half2*)qh)[(size_t)node * 8 + k] = __floats2half2_rn(qa0, qa1);
    }
  }
}

// ---- K3: agg2, 8 lanes/node -----------------------------------------------
__global__ __launch_bounds__(256) void agg2_kernel(const __half* __restrict__ ph,
                                                   const __half* __restrict__ qh,
                                                   const int* __restrict__ row_csr,
                                                   const int* __restrict__ row_end,
                                                   const int* __restrict__ srclist,
                                                   const float* __restrict__ b2,
                                                   const float* __restrict__ Wc,
                                                   __half* __restrict__ Uh,
                                                   __half* __restrict__ Vh, int N) {
  __shared__ float Wc_s[256], b_s[16];
  int t = threadIdx.x;
  if (t < 256) Wc_s[t] = Wc[t];
  if (t < 16) b_s[t] = b2[t];
  __syncthreads();
  int g = (blockIdx.x * 256 + t) >> 3;
  int k = t & 7;
  if (g >= N) return;
  int beg = row_csr[g], end = row_end[g];
  const __half2* ph2 = (const __half2*)ph;
  float a0 = 0.f, a1 = 0.f;
  int j = beg;
  for (; j + 4 <= end; j += 4) {
    int s0 = srclist[j], s1 = srclist[j + 1];
    int s2 = srclist[j + 2], s3 = srclist[j + 3];
    float2 v0 = __half22float2(ph2[(size_t)s0 * 8 + k]);
    float2 v1 = __half22float2(ph2[(size_t)s1 * 8 + k]);
    float2 v2 = __half22float2(ph2[(size_t)s2 * 8 + k]);
    float2 v3 = __half22float2(ph2[(size_t)s3 * 8 + k]);
    a0 += v0.x + v1.x + v2.x + v3.x;
    a1 += v0.y + v1.y + v2.y + v3.y;
  }
  for (; j < end; ++j) {
    float2 v = __half22float2(ph2[(size_t)srclist[j] * 8 + k]);
    a0 += v.x; a1 += v.y;
  }
  int deg = end - beg;
  float inv = 1.f / (float)(deg > 0 ? deg : 1);
  float2 qv = __half22float2(((const __half2*)qh)[(size_t)g * 8 + k]);
  float h0 = fmaxf(a0 * inv + b_s[2 * k]     + qv.x, 0.f);
  float h1 = fmaxf(a1 * inv + b_s[2 * k + 1] + qv.y, 0.f);
  int wb = (k < 4) ? 0 : 128;
  int c0 = 2 * (k & 3);
  float o0 = 0.f, o1 = 0.f;
#pragma unroll
  for (int kk2 = 0; kk2 < 8; ++kk2) {
    float ha = __shfl(h0, kk2, 8);
    float hb = __shfl(h1, kk2, 8);
    int r0 = wb + 2 * kk2 * 8, r1 = r0 + 8;
    o0 += ha * Wc_s[r0 + c0]     + hb * Wc_s[r1 + c0];
    o1 += ha * Wc_s[r0 + c0 + 1] + hb * Wc_s[r1 + c0 + 1];
  }
  __half2 o = __floats2half2_rn(o0, o1);
  if (k < 4) ((__half2*)Uh)[(size_t)g * 4 + k] = o;
  else       ((__half2*)Vh)[(size_t)g * 4 + (k - 4)] = o;
}

// ---- K4: edge_out, 4 edges/thread iteration-strided, nt ei loads ----------
#define EIL 4
__global__ __launch_bounds__(256) void edge_out_kernel(const int* __restrict__ ei,
                                                       const __half* __restrict__ Uh,
                                                       const __half* __restrict__ Vh,
                                                       const float* __restrict__ bc,
                                                       float* __restrict__ out, int E) {
  int base = blockIdx.x * (256 * EIL) + threadIdx.x;
  float4 c0 = ((const float4*)bc)[0], c1 = ((const float4*)bc)[1];
  int s[EIL], d[EIL];
#pragma unroll
  for (int ii = 0; ii < EIL; ++ii) {
    int e = base + ii * 256;
    s[ii] = (e < E) ? __builtin_nontemporal_load(ei + e) : 0;
    d[ii] = (e < E) ? __builtin_nontemporal_load(ei + E + e) : 0;
  }
  H8 u8[EIL], v8[EIL];
#pragma unroll
  for (int ii = 0; ii < EIL; ++ii) {
    u8[ii] = *(const H8*)(Uh + (size_t)s[ii] * 8);
    v8[ii] = *(const H8*)(Vh + (size_t)d[ii] * 8);
  }
#pragma unroll
  for (int ii = 0; ii < EIL; ++ii) {
    int e = base + ii * 256;
    if (e >= E) continue;
    float2 ua = __half22float2(u8[ii].a), ub = __half22float2(u8[ii].b);
    float2 uc = __half22float2(u8[ii].c), ud = __half22float2(u8[ii].d);
    float2 va = __half22float2(v8[ii].a), vb = __half22float2(v8[ii].b);
    float2 vc = __half22float2(v8[ii].c), vd = __half22float2(v8[ii].d);
    float tv[8];
    tv[0] = ua.x + va.x + c0.x; tv[1] = ua.y + va.y + c0.y;
    tv[2] = ub.x + vb.x + c0.z; tv[3] = ub.y + vb.y + c0.w;
    tv[4] = uc.x + vc.x + c1.x; tv[5] = uc.y + vc.y + c1.y;
    tv[6] = ud.x + vd.x + c1.z; tv[7] = ud.y + vd.y + c1.w;
    float m = tv[0];
#pragma unroll
    for (int c = 1; c < 8; ++c) m = fmaxf(m, tv[c]);
    float ssum = 0.f;
#pragma unroll
    for (int c = 0; c < 8; ++c) ssum += __expf(tv[c] - m);
    float lse = m + __logf(ssum);
    float4 o0 = make_float4(tv[0] - lse, tv[1] - lse, tv[2] - lse, tv[3] - lse);
    float4 o1 = make_float4(tv[4] - lse, tv[5] - lse, tv[6] - lse, tv[7] - lse);
    float4* op = (float4*)(out + (size_t)e * 8);
    op[0] = o0; op[1] = o1;
  }
}

extern "C" void kernel_launch(void* const* d_in, const int* in_sizes, int n_in,
                              void* d_out, int out_size, void* d_ws, size_t ws_size,
                              hipStream_t stream) {
  const float* x   = (const float*)d_in[0];
  const int*   ei  = (const int*)d_in[1];
  const float* W1l = (const float*)d_in[2];
  const float* b1  = (const float*)d_in[3];
  const float* W1r = (const float*)d_in[4];
  const float* W2l = (const float*)d_in[5];
  const float* b2  = (const float*)d_in[6];
  const float* W2r = (const float*)d_in[7];
  const float* Wc  = (const float*)d_in[8];
  const float* bc  = (const float*)d_in[9];
  float* out = (float*)d_out;

  const int N = in_sizes[0] / 128;   // 100000
  const int E = in_sizes[1] / 2;     // 3200000
  const size_t N16 = (size_t)N * 16;
  const int NB = (N + BUCKET_SZ - 1) >> BUCKET_BITS;   // 392
  const int chunk = (E + NBLK - 1) / NBLK;             // 6250

  // Workspace layout (all-half intermediates except elist/infra)
  __half* yh = (__half*)d_ws;            // N*16 half
  __half* ph = yh + N16;                 // N*16 half
  __half* zh = ph + N16;                 // N*16 half
  __half* qh = zh + N16;                 // N*16 half
  __half* Uh = qh + N16;                 // N*8 half
  __half* Vh = Uh + (size_t)N * 8;       // N*8 half
  int* gcur    = (int*)(Vh + (size_t)N * 8);  // NB
  int* elist   = gcur + NB;              // NB*CAP (padded bucket regions)
  int* row_csr = elist + (size_t)NB * CAP;  // N
  int* row_end = row_csr + N;            // N

  hipMemsetAsync(gcur, 0, NB * sizeof(int), stream);

  int lin1_blocks = (N + LIN_NODES - 1) / LIN_NODES;
  prep_kernel<<<NBLK + lin1_blocks, 512, 0, stream>>>(ei, gcur, elist, x, W1l,
                                                      W1r, yh, zh, E, N, NB,
                                                      chunk, NBLK);

  size_t smem = (CAP + 256 + 4) * sizeof(int) + 528 * sizeof(float);
  sortagg_kernel<<<NB, 512, smem, stream>>>(elist, gcur, row_csr, row_end,
                                            yh, zh, b1, W2l, W2r, ph, qh, N);

  int ngrid = (N * 8 + 255) / 256;
  agg2_kernel<<<ngrid, 256, 0, stream>>>(ph, qh, row_csr, row_end, elist,
                                         b2, Wc, Uh, Vh, N);

  int egrid = (E + 256 * EIL - 1) / (256 * EIL);
  edge_out_kernel<<<egrid, 256, 0, stream>>>(ei, Uh, Vh, bc, out, E);
}

// Round 19
// 170.310 us; speedup vs baseline: 1.0697x; 1.0697x over previous
//
#include <hip/hip_runtime.h>
#include <hip/hip_bf16.h>
#include <hip/hip_fp16.h>

// GraphSAGE edge classifier.
// v18 == v16 (best measured: 170.2us). v17's occupancy push regressed:
// halving lin1 nodes/block doubled per-block weight staging (25->50MB) —
// prep is latency-bound, not occupancy-capped. Reverting to the proven
// geometry: NBLK=320 (chunk 10000, 40KB stage), lin1 64 nodes/block.
//  K0 memset   : gcur[NB] = 0
//  K1 prep     : blocks [0,320): hist->exscan->reserve->LDS sort->segment write
//                blocks [320,..): lin1 (yh=half(x@W1l), zh=half(x@W1r))
//  K2 sortagg  : per-bucket LDS counting sort -> row_csr/row_end + coalesced
//                elist writeback + fused agg1 -> ph, qh
//  K3 agg2     : CSR gather mean(ph) -> h2=relu(+b2+qh) -> Uh, Vh
//  K4 edge_out : out = log_softmax(Uh[src] + Vh[dst] + bc), 4 edges/thread

#define NBLK 320          // binning chunks (chunk = 10000)
#define BUCKET_BITS 8
#define BUCKET_SZ 256     // nodes per bucket
#define CAP 9216          // entries per bucket region (mean 8192, +11 sigma)
#define MAXNB 512
#define CHUNK_MAX 10240

struct __align__(16) H8 { __half2 a, b, c, d; };

// ---- K1: heterogeneous {local-sort binning} + lin1 -------------------------
__global__ __launch_bounds__(512) void prep_kernel(const int* __restrict__ ei,
                                                   int* __restrict__ gcur,
                                                   int* __restrict__ elist,
                                                   const float* __restrict__ x,
                                                   const float* __restrict__ W1l,
                                                   const float* __restrict__ W1r,
                                                   __half* __restrict__ yh,
                                                   __half* __restrict__ zh,
                                                   int E, int N, int NB, int chunk,
                                                   int nbin) {
  __shared__ float smem[64 * 129 + 128 * 32];   // 49.4 KB, aliased
  int t = threadIdx.x;
  if ((int)blockIdx.x < nbin) {
    // ---- binning: hist -> exscan+reserve -> LDS sort -> segment write ----
    int* hist  = (int*)smem;            // MAXNB   (becomes local cursor)
    int* loc   = hist + MAXNB;          // MAXNB   (immutable local exscan)
    int* gbase = loc + MAXNB;           // MAXNB   (global dest base)
    int* wtmp  = gbase + MAXNB;         // 8
    int* stage = wtmp + 8;              // CHUNK_MAX
    int lane = t & 63, wid = t >> 6;
    for (int i = t; i < NB; i += 512) hist[i] = 0;
    __syncthreads();
    int s = blockIdx.x * chunk;
    int eend = s + chunk; if (eend > E) eend = E;
    int cnt = eend - s;
    for (int e = s + t; e < eend; e += 512)
      atomicAdd(&hist[ei[E + e] >> BUCKET_BITS], 1);
    __syncthreads();
    // exscan over NB bins (one element per thread, NB <= 512)
    {
      int v = (t < NB) ? hist[t] : 0;
      int incl = v;
#pragma unroll
      for (int d = 1; d < 64; d <<= 1) {
        int u = __shfl_up(incl, d);
        if (lane >= d) incl += u;
      }
      if (lane == 63) wtmp[wid] = incl;
      __syncthreads();
      if (t < 64) {
        int w = (t < 8) ? wtmp[t] : 0;
#pragma unroll
        for (int d = 1; d < 8; d <<= 1) {
          int u = __shfl_up(w, d);
          if (lane >= d) w += u;
        }
        if (t < 8) wtmp[t] = w;
      }
      __syncthreads();
      if (t < NB) {
        int excl = ((wid > 0) ? wtmp[wid - 1] : 0) + (incl - v);
        loc[t] = excl;
        gbase[t] = t * CAP + (v ? atomicAdd(&gcur[t], v) : 0);
        hist[t] = excl;                 // local scatter cursor
      }
    }
    __syncthreads();
    // local scatter into LDS stage (sorted by bucket)
    for (int e = s + t; e < eend; e += 512) {
      int src = ei[e];
      int dst = ei[E + e];
      int b = dst >> BUCKET_BITS;
      int pos = atomicAdd(&hist[b], 1);
      stage[pos] = ((dst & (BUCKET_SZ - 1)) << 17) | src;
    }
    __syncthreads();
    // segment-coalesced global write: position i belongs to bucket
    // lo = max{b : loc[b] <= i}; dest = gbase[lo] + (i - loc[lo]).
    for (int i = t; i < cnt; i += 512) {
      int lo = 0, hi = NB;
#pragma unroll 9
      while (hi - lo > 1) {
        int mid = (lo + hi) >> 1;
        if (loc[mid] <= i) lo = mid; else hi = mid;
      }
      elist[gbase[lo] + (i - loc[lo])] = stage[i];
    }
  } else {
    // ---- lin1: 64 nodes per block ----
    float* Xs = smem;                // 64*129
    float* Ws = smem + 64 * 129;     // 128*32
    int nb = ((int)blockIdx.x - nbin) * 64;
    for (int i = t; i < 128 * 16; i += 512) {
      int kk = i >> 4, c = i & 15;
      Ws[kk * 32 + c] = W1l[i];
      Ws[kk * 32 + 16 + c] = W1r[i];
    }
    const float4* xg = (const float4*)(x + (size_t)nb * 128);
    for (int i4 = t; i4 < 64 * 32; i4 += 512) {
      int r = i4 >> 5, c4 = (i4 & 31) * 4;
      float4 val = make_float4(0.f, 0.f, 0.f, 0.f);
      if (nb + r < N) val = xg[i4];
      float* dp = &Xs[r * 129 + c4];
      dp[0] = val.x; dp[1] = val.y; dp[2] = val.z; dp[3] = val.w;
    }
    __syncthreads();
    int n = t & 63, cg = t >> 6;
    float a0 = 0.f, a1 = 0.f, a2 = 0.f, a3 = 0.f;
    for (int kk = 0; kk < 128; ++kk) {
      float xv = Xs[n * 129 + kk];
      const float* wr = &Ws[kk * 32 + cg * 4];
      a0 += xv * wr[0]; a1 += xv * wr[1]; a2 += xv * wr[2]; a3 += xv * wr[3];
    }
    int node = nb + n;
    if (node < N) {
      int c = cg * 4;
      __half2 h01 = __floats2half2_rn(a0, a1);
      __half2 h23 = __floats2half2_rn(a2, a3);
      if (c < 16) {
        __half2* yp = (__half2*)(yh + (size_t)node * 16 + c);
        yp[0] = h01; yp[1] = h23;
      } else {
        __half2* zp = (__half2*)(zh + (size_t)node * 16 + (c - 16));
        zp[0] = h01; zp[1] = h23;
      }
    }
  }
}

// ---- K2: fused per-bucket counting sort + agg1 ------------------------------
__global__ __launch_bounds__(512) void sortagg_kernel(int* __restrict__ elist,
                                                      const int* __restrict__ gcur,
                                                      int* __restrict__ row_csr,
                                                      int* __restrict__ row_end,
                                                      const __half* __restrict__ yh,
                                                      const __half* __restrict__ zh,
                                                      const float* __restrict__ b1,
                                                      const float* __restrict__ W2l,
                                                      const float* __restrict__ W2r,
                                                      __half* __restrict__ ph,
                                                      __half* __restrict__ qh, int N) {
  extern __shared__ int sm[];
  int* sorted = sm;                    // CAP
  int* hist   = sm + CAP;              // 256
  int* wtmp   = hist + 256;            // 4
  float* Wl_s = (float*)(wtmp + 4);    // 256
  float* Wr_s = Wl_s + 256;            // 256
  float* b_s  = Wr_s + 256;            // 16
  int t = threadIdx.x;
  int b = blockIdx.x;
  int lane = t & 63, wid = t >> 6;
  if (t < 256) { Wl_s[t] = W2l[t]; Wr_s[t] = W2r[t]; hist[t] = 0; }
  else if (t < 272) b_s[t - 256] = b1[t - 256];
  int beg = b * CAP;
  int cnt = gcur[b];
  if (cnt > CAP) cnt = CAP;   // statistically unreachable
  __syncthreads();
  // pass 1: histogram from global
  for (int i = t; i < cnt; i += 512)
    atomicAdd(&hist[((unsigned)elist[beg + i]) >> 17], 1);
  __syncthreads();
  // exscan hist[0..255]
  {
    int v = (t < 256) ? hist[t] : 0;
    int incl = v;
#pragma unroll
    for (int d = 1; d < 64; d <<= 1) {
      int u = __shfl_up(incl, d);
      if (lane >= d) incl += u;
    }
    if (t < 256 && lane == 63) wtmp[wid] = incl;
    __syncthreads();
    if (t < 64) {
      int w = (t < 4) ? wtmp[t] : 0;
#pragma unroll
      for (int d = 1; d < 4; d <<= 1) {
        int u = __shfl_up(w, d);
        if (lane >= d) w += u;
      }
      if (t < 4) wtmp[t] = w;
    }
    __syncthreads();
    if (t < 256) {
      int excl = ((wid > 0) ? wtmp[wid - 1] : 0) + (incl - v);
      hist[t] = excl;                       // scatter cursor
      int node = (b << BUCKET_BITS) + t;
      if (node < N) row_csr[node] = beg + excl;
    }
  }
  __syncthreads();
  // pass 2: scatter from global (L2-hot) into LDS
  for (int i = t; i < cnt; i += 512) {
    unsigned ent = (unsigned)elist[beg + i];
    int pos = atomicAdd(&hist[ent >> 17], 1);
    sorted[pos] = ent & 0x1FFFF;
  }
  __syncthreads();
  if (t < 256) {
    int node = (b << BUCKET_BITS) + t;
    if (node < N) row_end[node] = beg + hist[t];
  }
  // coalesced writeback for agg2
  for (int i = t; i < cnt; i += 512) elist[beg + i] = sorted[i];
  // ---- fused agg1: 256 nodes, 8 lanes/node, 4 passes of 64 nodes ----
  const __half2* yh2 = (const __half2*)yh;
  int base = b << BUCKET_BITS;
  int k = t & 7;
#pragma unroll
  for (int pass = 0; pass < 4; ++pass) {
    int dl = pass * 64 + (t >> 3);
    int node = base + dl;
    if (node < N) {
      int rbeg = dl ? hist[dl - 1] : 0;   // hist = end offsets after scatter
      int rend = hist[dl];
      float a0 = 0.f, a1 = 0.f;
      int j = rbeg;
      for (; j + 4 <= rend; j += 4) {
        int s0 = sorted[j], s1 = sorted[j + 1];
        int s2 = sorted[j + 2], s3 = sorted[j + 3];
        float2 v0 = __half22float2(yh2[(size_t)s0 * 8 + k]);
        float2 v1 = __half22float2(yh2[(size_t)s1 * 8 + k]);
        float2 v2 = __half22float2(yh2[(size_t)s2 * 8 + k]);
        float2 v3 = __half22float2(yh2[(size_t)s3 * 8 + k]);
        a0 += v0.x + v1.x + v2.x + v3.x;
        a1 += v0.y + v1.y + v2.y + v3.y;
      }
      for (; j < rend; ++j) {
        float2 v = __half22float2(yh2[(size_t)sorted[j] * 8 + k]);
        a0 += v.x; a1 += v.y;
      }
      int deg = rend - rbeg;
      float inv = 1.f / (float)(deg > 0 ? deg : 1);
      float2 zv = __half22float2(((const __half2*)zh)[(size_t)node * 8 + k]);
      float h0 = fmaxf(a0 * inv + b_s[2 * k]     + zv.x, 0.f);
      float h1 = fmaxf(a1 * inv + b_s[2 * k + 1] + zv.y, 0.f);
      float pa0 = 0.f, pa1 = 0.f, qa0 = 0.f, qa1 = 0.f;
      int c0 = 2 * k;
#pragma unroll
      for (int kk2 = 0; kk2 < 8; ++kk2) {
        float ha = __shfl(h0, kk2, 8);
        float hb = __shfl(h1, kk2, 8);
        int r0 = 2 * kk2 * 16, r1 = r0 + 16;
        pa0 += ha * Wl_s[r0 + c0]     + hb * Wl_s[r1 + c0];
        pa1 += ha * Wl_s[r0 + c0 + 1] + hb * Wl_s[r1 + c0 + 1];
        qa0 += ha * Wr_s[r0 + c0]     + hb * Wr_s[r1 + c0];
        qa1 += ha * Wr_s[r0 + c0 + 1] + hb * Wr_s[r1 + c0 + 1];
      }
      ((__half2*)ph)[(size_t)node * 8 + k] = __floats2half2_rn(pa0, pa1);
      ((__half2*)qh)[(size_t)node * 8 + k] = __floats2half2_rn(qa0, qa1);
    }
  }
}

// ---- K3: agg2, 8 lanes/node -----------------------------------------------
__global__ __launch_bounds__(256) void agg2_kernel(const __half* __restrict__ ph,
                                                   const __half* __restrict__ qh,
                                                   const int* __restrict__ row_csr,
                                                   const int* __restrict__ row_end,
                                                   const int* __restrict__ srclist,
                                                   const float* __restrict__ b2,
                                                   const float* __restrict__ Wc,
                                                   __half* __restrict__ Uh,
                                                   __half* __restrict__ Vh, int N) {
  __shared__ float Wc_s[256], b_s[16];
  int t = threadIdx.x;
  if (t < 256) Wc_s[t] = Wc[t];
  if (t < 16) b_s[t] = b2[t];
  __syncthreads();
  int g = (blockIdx.x * 256 + t) >> 3;
  int k = t & 7;
  if (g >= N) return;
  int beg = row_csr[g], end = row_end[g];
  const __half2* ph2 = (const __half2*)ph;
  float a0 = 0.f, a1 = 0.f;
  int j = beg;
  for (; j + 4 <= end; j += 4) {
    int s0 = srclist[j], s1 = srclist[j + 1];
    int s2 = srclist[j + 2], s3 = srclist[j + 3];
    float2 v0 = __half22float2(ph2[(size_t)s0 * 8 + k]);
    float2 v1 = __half22float2(ph2[(size_t)s1 * 8 + k]);
    float2 v2 = __half22float2(ph2[(size_t)s2 * 8 + k]);
    float2 v3 = __half22float2(ph2[(size_t)s3 * 8 + k]);
    a0 += v0.x + v1.x + v2.x + v3.x;
    a1 += v0.y + v1.y + v2.y + v3.y;
  }
  for (; j < end; ++j) {
    float2 v = __half22float2(ph2[(size_t)srclist[j] * 8 + k]);
    a0 += v.x; a1 += v.y;
  }
  int deg = end - beg;
  float inv = 1.f / (float)(deg > 0 ? deg : 1);
  float2 qv = __half22float2(((const __half2*)qh)[(size_t)g * 8 + k]);
  float h0 = fmaxf(a0 * inv + b_s[2 * k]     + qv.x, 0.f);
  float h1 = fmaxf(a1 * inv + b_s[2 * k + 1] + qv.y, 0.f);
  int wb = (k < 4) ? 0 : 128;
  int c0 = 2 * (k & 3);
  float o0 = 0.f, o1 = 0.f;
#pragma unroll
  for (int kk2 = 0; kk2 < 8; ++kk2) {
    float ha = __shfl(h0, kk2, 8);
    float hb = __shfl(h1, kk2, 8);
    int r0 = wb + 2 * kk2 * 8, r1 = r0 + 8;
    o0 += ha * Wc_s[r0 + c0]     + hb * Wc_s[r1 + c0];
    o1 += ha * Wc_s[r0 + c0 + 1] + hb * Wc_s[r1 + c0 + 1];
  }
  __half2 o = __floats2half2_rn(o0, o1);
  if (k < 4) ((__half2*)Uh)[(size_t)g * 4 + k] = o;
  else       ((__half2*)Vh)[(size_t)g * 4 + (k - 4)] = o;
}

// ---- K4: edge_out, 4 edges/thread iteration-strided, nt ei loads ----------
#define EIL 4
__global__ __launch_bounds__(256) void edge_out_kernel(const int* __restrict__ ei,
                                                       const __half* __restrict__ Uh,
                                                       const __half* __restrict__ Vh,
                                                       const float* __restrict__ bc,
                                                       float* __restrict__ out, int E) {
  int base = blockIdx.x * (256 * EIL) + threadIdx.x;
  float4 c0 = ((const float4*)bc)[0], c1 = ((const float4*)bc)[1];
  int s[EIL], d[EIL];
#pragma unroll
  for (int ii = 0; ii < EIL; ++ii) {
    int e = base + ii * 256;
    s[ii] = (e < E) ? __builtin_nontemporal_load(ei + e) : 0;
    d[ii] = (e < E) ? __builtin_nontemporal_load(ei + E + e) : 0;
  }
  H8 u8[EIL], v8[EIL];
#pragma unroll
  for (int ii = 0; ii < EIL; ++ii) {
    u8[ii] = *(const H8*)(Uh + (size_t)s[ii] * 8);
    v8[ii] = *(const H8*)(Vh + (size_t)d[ii] * 8);
  }
#pragma unroll
  for (int ii = 0; ii < EIL; ++ii) {
    int e = base + ii * 256;
    if (e >= E) continue;
    float2 ua = __half22float2(u8[ii].a), ub = __half22float2(u8[ii].b);
    float2 uc = __half22float2(u8[ii].c), ud = __half22float2(u8[ii].d);
    float2 va = __half22float2(v8[ii].a), vb = __half22float2(v8[ii].b);
    float2 vc = __half22float2(v8[ii].c), vd = __half22float2(v8[ii].d);
    float tv[8];
    tv[0] = ua.x + va.x + c0.x; tv[1] = ua.y + va.y + c0.y;
    tv[2] = ub.x + vb.x + c0.z; tv[3] = ub.y + vb.y + c0.w;
    tv[4] = uc.x + vc.x + c1.x; tv[5] = uc.y + vc.y + c1.y;
    tv[6] = ud.x + vd.x + c1.z; tv[7] = ud.y + vd.y + c1.w;
    float m = tv[0];
#pragma unroll
    for (int c = 1; c < 8; ++c) m = fmaxf(m, tv[c]);
    float ssum = 0.f;
#pragma unroll
    for (int c = 0; c < 8; ++c) ssum += __expf(tv[c] - m);
    float lse = m + __logf(ssum);
    float4 o0 = make_float4(tv[0] - lse, tv[1] - lse, tv[2] - lse, tv[3] - lse);
    float4 o1 = make_float4(tv[4] - lse, tv[5] - lse, tv[6] - lse, tv[7] - lse);
    float4* op = (float4*)(out + (size_t)e * 8);
    op[0] = o0; op[1] = o1;
  }
}

extern "C" void kernel_launch(void* const* d_in, const int* in_sizes, int n_in,
                              void* d_out, int out_size, void* d_ws, size_t ws_size,
                              hipStream_t stream) {
  const float* x   = (const float*)d_in[0];
  const int*   ei  = (const int*)d_in[1];
  const float* W1l = (const float*)d_in[2];
  const float* b1  = (const float*)d_in[3];
  const float* W1r = (const float*)d_in[4];
  const float* W2l = (const float*)d_in[5];
  const float* b2  = (const float*)d_in[6];
  const float* W2r = (const float*)d_in[7];
  const float* Wc  = (const float*)d_in[8];
  const float* bc  = (const float*)d_in[9];
  float* out = (float*)d_out;

  const int N = in_sizes[0] / 128;   // 100000
  const int E = in_sizes[1] / 2;     // 3200000
  const size_t N16 = (size_t)N * 16;
  const int NB = (N + BUCKET_SZ - 1) >> BUCKET_BITS;   // 392
  const int chunk = (E + NBLK - 1) / NBLK;             // 10000

  // Workspace layout (all-half intermediates except elist/infra)
  __half* yh = (__half*)d_ws;            // N*16 half
  __half* ph = yh + N16;                 // N*16 half
  __half* zh = ph + N16;                 // N*16 half
  __half* qh = zh + N16;                 // N*16 half
  __half* Uh = qh + N16;                 // N*8 half
  __half* Vh = Uh + (size_t)N * 8;       // N*8 half
  int* gcur    = (int*)(Vh + (size_t)N * 8);  // NB
  int* elist   = gcur + NB;              // NB*CAP (padded bucket regions)
  int* row_csr = elist + (size_t)NB * CAP;  // N
  int* row_end = row_csr + N;            // N

  hipMemsetAsync(gcur, 0, NB * sizeof(int), stream);

  int lin1_blocks = (N + 63) / 64;
  prep_kernel<<<NBLK + lin1_blocks, 512, 0, stream>>>(ei, gcur, elist, x, W1l,
                                                      W1r, yh, zh, E, N, NB,
                                                      chunk, NBLK);

  size_t smem = (CAP + 256 + 4) * sizeof(int) + 528 * sizeof(float);
  sortagg_kernel<<<NB, 512, smem, stream>>>(elist, gcur, row_csr, row_end,
                                            yh, zh, b1, W2l, W2r, ph, qh, N);

  int ngrid = (N * 8 + 255) / 256;
  agg2_kernel<<<ngrid, 256, 0, stream>>>(ph, qh, row_csr, row_end, elist,
                                         b2, Wc, Uh, Vh, N);

  int egrid = (E + 256 * EIL - 1) / (256 * EIL);
  edge_out_kernel<<<egrid, 256, 0, stream>>>(ei, Uh, Vh, bc, out, E);
}